// Round 7
// baseline (338.790 us; speedup 1.0000x reference)
//
#include <hip/hip_runtime.h>
#include <hip/hip_bf16.h>
#include <math.h>

#define DMODEL 256
#define NH 8
#define DKH 32
#define SEQ 197
#define BATCH 64
#define NPAT 196
#define FFDIM 1024
#define KCONV 768
#define EPSLN 1e-5f
#define MROWS (BATCH * SEQ)  // 12608 = 197*64
#define SP 224               // SEQ padded to 7 super-tiles of 32

typedef __attribute__((ext_vector_type(8))) short short8;
typedef __attribute__((ext_vector_type(4))) short short4v;
typedef __attribute__((ext_vector_type(4))) float floatx4;

__device__ inline short f2b(float f) {
  unsigned u = __float_as_uint(f);
  unsigned r = (u + 0x7FFFu + ((u >> 16) & 1u)) >> 16;
  return (short)r;
}
__device__ inline float b2f(short s) {
  return __uint_as_float(((unsigned)(unsigned short)s) << 16);
}

// async global->LDS 16B DMA (lds dest: wave-uniform base + lane*16)
typedef const __attribute__((address_space(1))) unsigned int gu32;
typedef __attribute__((address_space(3))) unsigned int lu32;
__device__ __forceinline__ void gl_lds16(const void* g, void* l) {
  __builtin_amdgcn_global_load_lds((gu32*)g, (lu32*)l, 16, 0, 0);
}

// ---------------------------------------------------------------------------
// Pipelined 64x64 bf16 MFMA GEMM body, BK=64, double-buffered LDS.
// ---------------------------------------------------------------------------
__device__ __forceinline__ void gemm64_body(
    char* smem, int bx, int by,
    const short* __restrict__ A, const short* __restrict__ W,
    const float* __restrict__ bias, const short* __restrict__ resb,
    float* __restrict__ outf, short* __restrict__ outb,
    int N, int K, int relu)
{
  short* Al = (short*)smem;            // 2 x 4096 shorts
  short* Bl = (short*)(smem + 16384);  // 2 x 4096 shorts
  const int t = threadIdx.x;
  const int wave = t >> 6, lane = t & 63;
  const int wm = (wave & 1) * 32, wn = (wave >> 1) * 32;
  const int ml = lane & 15, quad = lane >> 4;
  const int m7 = ml & 7;
  const int m0 = bx * 64, n0 = by * 64;

  const int rs = t >> 3;
  const int cs = (t & 7) ^ (rs & 7);
  const short* gA0 = A + (size_t)(m0 + rs) * K + cs * 8;
  const short* gA1 = A + (size_t)(m0 + rs + 32) * K + cs * 8;
  const short* gB0 = W + (size_t)(n0 + rs) * K + cs * 8;
  const short* gB1 = W + (size_t)(n0 + rs + 32) * K + cs * 8;

  int offA[2][2], offB[2][2];
#pragma unroll
  for (int kk = 0; kk < 2; kk++)
#pragma unroll
    for (int i = 0; i < 2; i++) {
      int ra = wm + i * 16 + ml;
      offA[kk][i] = ra * 64 + (((kk * 4 + quad) ^ m7) * 8);
      int rb = wn + i * 16 + ml;
      offB[kk][i] = rb * 64 + (((kk * 4 + quad) ^ m7) * 8);
    }

  floatx4 z = {0.f, 0.f, 0.f, 0.f};
  floatx4 acc[2][2] = {{z, z}, {z, z}};

  const int niter = K >> 6;
  gl_lds16(gA0, Al + t * 8);
  gl_lds16(gA1, Al + t * 8 + 2048);
  gl_lds16(gB0, Bl + t * 8);
  gl_lds16(gB1, Bl + t * 8 + 2048);
  for (int k = 0; k < niter; k++) {
    int cur = k & 1;
    if (k + 1 < niter) {
      int nb = (cur ^ 1) * 4096;
      int k0 = (k + 1) << 6;
      gl_lds16(gA0 + k0, Al + nb + t * 8);
      gl_lds16(gA1 + k0, Al + nb + t * 8 + 2048);
      gl_lds16(gB0 + k0, Bl + nb + t * 8);
      gl_lds16(gB1 + k0, Bl + nb + t * 8 + 2048);
      __builtin_amdgcn_s_waitcnt(0x0F74);  // vmcnt(4)
    } else {
      __builtin_amdgcn_s_waitcnt(0x0F70);  // vmcnt(0)
    }
    __asm__ volatile("s_barrier" ::: "memory");
    const short* Ac = Al + cur * 4096;
    const short* Bc = Bl + cur * 4096;
#pragma unroll
    for (int kk = 0; kk < 2; kk++) {
      short8 a0 = *(const short8*)&Ac[offA[kk][0]];
      short8 a1 = *(const short8*)&Ac[offA[kk][1]];
      short8 b0 = *(const short8*)&Bc[offB[kk][0]];
      short8 b1 = *(const short8*)&Bc[offB[kk][1]];
      acc[0][0] = __builtin_amdgcn_mfma_f32_16x16x32_bf16(a0, b0, acc[0][0], 0, 0, 0);
      acc[0][1] = __builtin_amdgcn_mfma_f32_16x16x32_bf16(a0, b1, acc[0][1], 0, 0, 0);
      acc[1][0] = __builtin_amdgcn_mfma_f32_16x16x32_bf16(a1, b0, acc[1][0], 0, 0, 0);
      acc[1][1] = __builtin_amdgcn_mfma_f32_16x16x32_bf16(a1, b1, acc[1][1], 0, 0, 0);
    }
    __asm__ volatile("s_barrier" ::: "memory");
  }
#pragma unroll
  for (int i = 0; i < 2; i++)
#pragma unroll
    for (int j = 0; j < 2; j++)
#pragma unroll
      for (int rr = 0; rr < 4; rr++) {
        int row = m0 + wm + i * 16 + quad * 4 + rr;
        int col = n0 + wn + j * 16 + ml;
        float v = acc[i][j][rr] + bias[col];
        if (resb) v += b2f(resb[(size_t)row * N + col]);
        if (relu) v = fmaxf(v, 0.f);
        if (outf) outf[(size_t)row * N + col] = v;
        if (outb) outb[(size_t)row * N + col] = f2b(v);
      }
}

// ---------------------------------------------------------------------------
// Full-N (256) GEMM + fused LayerNorm epilogue. Block = 64 rows x 256 cols,
// BK=32, double-buffered (40 KB LDS), vmcnt(5) prefetch + raw s_barrier.
// Each wave owns 16 complete rows -> in-wave LN (shfl_xor 1,2,4,8).
// C = LN( A@W^T + bias + resb )  -> outb bf16 and/or outfin fp32.
// ---------------------------------------------------------------------------
__device__ __forceinline__ void gemm_full_body(
    char* smem, int bx,
    const short* __restrict__ A, const short* __restrict__ W,
    const float* __restrict__ bias, const short* __restrict__ resb,
    const float* __restrict__ g, const float* __restrict__ bln,
    short* __restrict__ outb, float* __restrict__ outfin, int K)
{
  short* Al = (short*)smem;           // 2 x 2048 shorts (64x32)
  short* Bl = (short*)(smem + 8192);  // 2 x 8192 shorts (256x32)
  const int t = threadIdx.x;
  const int wave = t >> 6, lane = t & 63;
  const int ml = lane & 15, quad = lane >> 4;
  const int m0 = bx * 64;

  const int rs = t >> 2;                  // 0..63
  const int cs = (t & 3) ^ (rs & 3);      // global chunk (swizzled)
  const short* gA = A + (size_t)(m0 + rs) * K + cs * 8;
  const short* gB[4];
#pragma unroll
  for (int j = 0; j < 4; j++)
    gB[j] = W + (size_t)(j * 64 + rs) * K + cs * 8;

  const int offA = (wave * 16 + ml) * 32 + ((quad ^ (ml & 3)) * 8);
  const int offBb = ml * 32 + ((quad ^ (ml & 3)) * 8);  // + jj*512

  floatx4 zv = {0.f, 0.f, 0.f, 0.f};
  floatx4 acc[16];
#pragma unroll
  for (int jj = 0; jj < 16; jj++) acc[jj] = zv;

  const int niter = K >> 5;
  gl_lds16(gA, Al + t * 8);
#pragma unroll
  for (int j = 0; j < 4; j++) gl_lds16(gB[j], Bl + j * 2048 + t * 8);
  for (int k = 0; k < niter; k++) {
    int cur = k & 1;
    if (k + 1 < niter) {
      int k0 = (k + 1) << 5;
      int nbA = (cur ^ 1) * 2048, nbB = (cur ^ 1) * 8192;
      gl_lds16(gA + k0, Al + nbA + t * 8);
#pragma unroll
      for (int j = 0; j < 4; j++) gl_lds16(gB[j] + k0, Bl + nbB + j * 2048 + t * 8);
      __builtin_amdgcn_s_waitcnt(0x0F75);  // vmcnt(5)
    } else {
      __builtin_amdgcn_s_waitcnt(0x0F70);  // vmcnt(0)
    }
    __asm__ volatile("s_barrier" ::: "memory");
    const short* Ac = Al + cur * 2048;
    const short* Bc = Bl + cur * 8192;
    short8 a = *(const short8*)&Ac[offA];
#pragma unroll
    for (int jj = 0; jj < 16; jj++) {
      short8 b = *(const short8*)&Bc[offBb + jj * 512];
      acc[jj] = __builtin_amdgcn_mfma_f32_16x16x32_bf16(a, b, acc[jj], 0, 0, 0);
    }
    __asm__ volatile("s_barrier" ::: "memory");
  }

  // ---- epilogue: bias + residual, then per-row LayerNorm ----
  const int rbase = m0 + wave * 16 + quad * 4;
  float bias_r[16], g_r[16], bl_r[16];
#pragma unroll
  for (int jj = 0; jj < 16; jj++) {
    int c = jj * 16 + ml;
    bias_r[jj] = bias[c];
    g_r[jj] = g[c];
    bl_r[jj] = bln[c];
  }
#pragma unroll
  for (int jj = 0; jj < 16; jj++)
#pragma unroll
    for (int rr = 0; rr < 4; rr++)
      acc[jj][rr] += bias_r[jj] + b2f(resb[(size_t)(rbase + rr) * DMODEL + jj * 16 + ml]);
#pragma unroll
  for (int rr = 0; rr < 4; rr++) {
    float s = 0.f;
#pragma unroll
    for (int jj = 0; jj < 16; jj++) s += acc[jj][rr];
    s += __shfl_xor(s, 1); s += __shfl_xor(s, 2);
    s += __shfl_xor(s, 4); s += __shfl_xor(s, 8);
    float mean = s * (1.0f / DMODEL);
    float vs = 0.f;
#pragma unroll
    for (int jj = 0; jj < 16; jj++) {
      float d = acc[jj][rr] - mean;
      vs += d * d;
    }
    vs += __shfl_xor(vs, 1); vs += __shfl_xor(vs, 2);
    vs += __shfl_xor(vs, 4); vs += __shfl_xor(vs, 8);
    float inv = rsqrtf(vs * (1.0f / DMODEL) + EPSLN);
    int row = rbase + rr;
#pragma unroll
    for (int jj = 0; jj < 16; jj++) {
      float o = (acc[jj][rr] - mean) * inv * g_r[jj] + bl_r[jj];
      int col = jj * 16 + ml;
      if (outb) outb[(size_t)row * DMODEL + col] = f2b(o);
      if (outfin) outfin[(size_t)row * DMODEL + col] = o;
    }
  }
}

// ---------------------------------------------------------------------------
// Patch-embed conv as 64x64 MFMA GEMM body, BK=64, im2col from fp32 img.
// ---------------------------------------------------------------------------
__device__ __forceinline__ void conv64_body(
    char* smem, int bx, int by,
    const float* __restrict__ img, const short* __restrict__ W,
    const float* __restrict__ cb, const float* __restrict__ pos,
    short* __restrict__ e)
{
  short* Al = (short*)smem;           // 4096 shorts
  short* Bl = (short*)(smem + 8192);  // 4096 shorts
  const int t = threadIdx.x;
  const int wave = t >> 6, lane = t & 63;
  const int wm = (wave & 1) * 32, wn = (wave >> 1) * 32;
  const int ml = lane & 15, quad = lane >> 4;
  const int m7 = ml & 7;
  const int m0 = bx * 64, n0 = by * 64;

  int rA = t >> 3, cg = t & 7;
  int pr_off = cg >> 1;
  int px_off = (cg & 1) * 8;
  int csw = cg ^ (rA & 7);
  const float* baseA[2];
  short* lA[2];
#pragma unroll
  for (int p = 0; p < 2; p++) {
    int m = m0 + rA + p * 32;
    int b = m / NPAT, pp = m - b * NPAT;
    int py = pp / 14, px = pp - py * 14;
    baseA[p] = img + (size_t)b * 3 * 50176 + (size_t)(py * 16) * 224 + px * 16 + px_off;
    lA[p] = &Al[(rA + p * 32) * 64 + csw * 8];
  }
  int rs = t >> 3;
  int cs = (t & 7) ^ (rs & 7);
  const short* gB0 = W + (size_t)(n0 + rs) * KCONV + cs * 8;
  const short* gB1 = W + (size_t)(n0 + rs + 32) * KCONV + cs * 8;

  int offA[2][2], offB[2][2];
#pragma unroll
  for (int kk = 0; kk < 2; kk++)
#pragma unroll
    for (int i = 0; i < 2; i++) {
      int ra = wm + i * 16 + ml;
      offA[kk][i] = ra * 64 + (((kk * 4 + quad) ^ m7) * 8);
      int rb = wn + i * 16 + ml;
      offB[kk][i] = rb * 64 + (((kk * 4 + quad) ^ m7) * 8);
    }

  floatx4 z = {0.f, 0.f, 0.f, 0.f};
  floatx4 acc[2][2] = {{z, z}, {z, z}};

  for (int k0 = 0; k0 < KCONV; k0 += 64) {
    int ch = k0 >> 8;
    int rr0 = (k0 & 255) >> 4;
    __syncthreads();
    gl_lds16(gB0 + k0, Bl + t * 8);
    gl_lds16(gB1 + k0, Bl + t * 8 + 2048);
#pragma unroll
    for (int p = 0; p < 2; p++) {
      const float* ap = baseA[p] + (size_t)ch * 50176 + (rr0 + pr_off) * 224;
      float4 a0 = *(const float4*)ap;
      float4 a1 = *(const float4*)(ap + 4);
      short8 av;
      av[0] = f2b(a0.x); av[1] = f2b(a0.y); av[2] = f2b(a0.z); av[3] = f2b(a0.w);
      av[4] = f2b(a1.x); av[5] = f2b(a1.y); av[6] = f2b(a1.z); av[7] = f2b(a1.w);
      *(short8*)lA[p] = av;
    }
    __builtin_amdgcn_s_waitcnt(0x0F70);
    __syncthreads();
#pragma unroll
    for (int kk = 0; kk < 2; kk++) {
      short8 a0 = *(const short8*)&Al[offA[kk][0]];
      short8 a1 = *(const short8*)&Al[offA[kk][1]];
      short8 b0 = *(const short8*)&Bl[offB[kk][0]];
      short8 b1 = *(const short8*)&Bl[offB[kk][1]];
      acc[0][0] = __builtin_amdgcn_mfma_f32_16x16x32_bf16(a0, b0, acc[0][0], 0, 0, 0);
      acc[0][1] = __builtin_amdgcn_mfma_f32_16x16x32_bf16(a0, b1, acc[0][1], 0, 0, 0);
      acc[1][0] = __builtin_amdgcn_mfma_f32_16x16x32_bf16(a1, b0, acc[1][0], 0, 0, 0);
      acc[1][1] = __builtin_amdgcn_mfma_f32_16x16x32_bf16(a1, b1, acc[1][1], 0, 0, 0);
    }
  }
#pragma unroll
  for (int i = 0; i < 2; i++)
#pragma unroll
    for (int j = 0; j < 2; j++)
#pragma unroll
      for (int rr = 0; rr < 4; rr++) {
        int mrow = m0 + wm + i * 16 + quad * 4 + rr;
        int b2 = mrow / NPAT, p2 = mrow - b2 * NPAT;
        int col = n0 + wn + j * 16 + ml;
        e[((size_t)b2 * SEQ + p2) * DMODEL + col] =
            f2b(acc[i][j][rr] + cb[col] + pos[p2 * DMODEL + col]);
      }
}

// ---------------------------------------------------------------------------
// MFMA flash attention body, S^T formulation. bid2 in [0,1024).
// ---------------------------------------------------------------------------
__device__ __forceinline__ void attn_body(
    char* smem, int bid2,
    const short* __restrict__ qp, int qstr,
    const short* __restrict__ kp, int kstr,
    const short* __restrict__ vp, int vstr,
    const unsigned long long* __restrict__ mbits,
    short* __restrict__ op)
{
  short (*ks)[40] = (short(*)[40])smem;                     // SP*40 = 17920 B
  short (*vt)[SP + 8] = (short(*)[SP + 8])(smem + 17920);   // 32*232 = 14848 B
  short* psw = (short*)(smem + 32768);                      // 4*640 = 5120 B
  int bh = bid2 >> 1, half = bid2 & 1;
  int b = bh >> 3, h = bh & 7;
  int t = threadIdx.x;
  int wave = t >> 6, lane = t & 63;
  int ml = lane & 15, quad = lane >> 4;
  short* ps = psw + wave * 640;

  const short* kb = kp + (size_t)b * SEQ * kstr + h * DKH;
  const short* vb = vp + (size_t)b * SEQ * vstr + h * DKH;
  for (int idx = t; idx < SEQ * 4; idx += 256) {
    int s = idx >> 2, c = (idx & 3) * 8;
    *(short8*)&ks[s][c] = *(const short8*)(kb + (size_t)s * kstr + c);
  }
  for (int idx = t; idx < SEQ * 4; idx += 256) {
    int s = idx >> 2, c = (idx & 3) * 8;
    short8 v8 = *(const short8*)(vb + (size_t)s * vstr + c);
#pragma unroll
    for (int j = 0; j < 8; j++) vt[c + j][s] = v8[j];
  }
  for (int idx = t; idx < DKH * (SP - SEQ); idx += 256) {
    int d = idx / (SP - SEQ), j = SEQ + idx - d * (SP - SEQ);
    vt[d][j] = 0;
  }
  __syncthreads();

  const float scale = 0.17677669529663687f;
  floatx4 z = {0.f, 0.f, 0.f, 0.f};

  for (int tt = 0; tt < 2; tt++) {
    int ti = half * 8 + wave * 2 + tt;
    int q0 = ti * 16;
    if (q0 >= SEQ) continue;
    int qrow = q0 + ml;
    int qc = qrow < SEQ ? qrow : SEQ - 1;
    short8 qf = *(const short8*)(qp + ((size_t)b * SEQ + qc) * qstr + h * DKH + quad * 8);
    const unsigned long long* mrow = mbits + (size_t)qc * 4;

    floatx4 accO0 = z, accO1 = z;
    float mrun = -1e30f, lrun = 0.f;

    for (int st = 0; st < 7; st++) {
      int j0 = st * 32;
      short8 k0 = *(const short8*)&ks[j0 + ml][quad * 8];
      short8 k1 = *(const short8*)&ks[j0 + 16 + ml][quad * 8];
      floatx4 s0 = __builtin_amdgcn_mfma_f32_16x16x32_bf16(k0, qf, z, 0, 0, 0);
      floatx4 s1 = __builtin_amdgcn_mfma_f32_16x16x32_bf16(k1, qf, z, 0, 0, 0);
      unsigned long long mb = mrow[j0 >> 6] >> (j0 & 63);
      float sv[8];
#pragma unroll
      for (int r = 0; r < 4; r++) {
        int jl = quad * 4 + r;
        sv[r]     = ((mb >> jl) & 1ull)        ? s0[r] * scale : -1e38f;
        sv[4 + r] = ((mb >> (16 + jl)) & 1ull) ? s1[r] * scale : -1e38f;
      }
      float tm = sv[0];
#pragma unroll
      for (int i = 1; i < 8; i++) tm = fmaxf(tm, sv[i]);
      tm = fmaxf(tm, __shfl_xor(tm, 16));
      tm = fmaxf(tm, __shfl_xor(tm, 32));
      float nm = fmaxf(mrun, tm);
      float alpha = __expf(mrun - nm);
      float pv[8];
      float psum = 0.f;
#pragma unroll
      for (int i = 0; i < 8; i++) { pv[i] = __expf(sv[i] - nm); psum += pv[i]; }
      psum += __shfl_xor(psum, 16);
      psum += __shfl_xor(psum, 32);
      lrun = lrun * alpha + psum;
      mrun = nm;
      accO0 = accO0 * alpha;
      accO1 = accO1 * alpha;
      short4v p0, p1;
#pragma unroll
      for (int r = 0; r < 4; r++) { p0[r] = f2b(pv[r]); p1[r] = f2b(pv[4 + r]); }
      *(short4v*)&ps[ml * 40 + quad * 4]      = p0;
      *(short4v*)&ps[ml * 40 + 16 + quad * 4] = p1;
      __asm__ volatile("s_waitcnt lgkmcnt(0)" ::: "memory");
      short8 pf = *(const short8*)&ps[ml * 40 + quad * 8];
      short8 vf0 = *(const short8*)&vt[ml][j0 + quad * 8];
      short8 vf1 = *(const short8*)&vt[16 + ml][j0 + quad * 8];
      accO0 = __builtin_amdgcn_mfma_f32_16x16x32_bf16(vf0, pf, accO0, 0, 0, 0);
      accO1 = __builtin_amdgcn_mfma_f32_16x16x32_bf16(vf1, pf, accO1, 0, 0, 0);
    }
    if (qrow < SEQ) {
      float inv = 1.f / lrun;
      short* ob = op + ((size_t)b * SEQ + qrow) * DMODEL + h * DKH;
      short4v o0, o1;
#pragma unroll
      for (int r = 0; r < 4; r++) {
        o0[r] = f2b(accO0[r] * inv);
        o1[r] = f2b(accO1[r] * inv);
      }
      *(short4v*)(ob + quad * 4)      = o0;
      *(short4v*)(ob + 16 + quad * 4) = o1;
    }
  }
}

// ---------------------------------------------------------------------------
// Phase 0: weight prep + mask pack + cls row + dec fp32->bf16
// ---------------------------------------------------------------------------
__global__ __launch_bounds__(256) void phase0(
    const float* wq1, const float* wk1, const float* wv1,
    const float* bq1, const float* bk1, const float* bv1,
    const float* wq2, const float* wk2, const float* bq2, const float* bk2,
    const float* wv2s, const float* wo1, const float* wo2,
    const float* ffw1, const float* ffw2, const float* convw,
    short* Wqkv1, float* Bqkv1, short* Wqk2, float* Bqk2,
    short* Wv2, short* Wo1, short* Wo2, short* Wff1, short* Wff2, short* Wconv,
    const int* mask, unsigned long long* bits, unsigned long long* ones,
    const float* cls, const float* pos, short* e,
    const float* dec, short* dec_bf)
{
  int bid = blockIdx.x;
  int t = threadIdx.x;
  if (bid < 1024) {
    int i = bid * 256 + t;
    if (i < 65536) {
      Wqkv1[i] = f2b(wq1[i]); Wqkv1[65536 + i] = f2b(wk1[i]); Wqkv1[131072 + i] = f2b(wv1[i]);
      Wqk2[i] = f2b(wq2[i]);  Wqk2[65536 + i] = f2b(wk2[i]);
      Wv2[i] = f2b(wv2s[i]);  Wo1[i] = f2b(wo1[i]);  Wo2[i] = f2b(wo2[i]);
    }
    Wff1[i] = f2b(ffw1[i]); Wff2[i] = f2b(ffw2[i]);
    if (i < 196608) Wconv[i] = f2b(convw[i]);
    if (i < 256) {
      Bqkv1[i] = bq1[i]; Bqkv1[256 + i] = bk1[i]; Bqkv1[512 + i] = bv1[i];
      Bqk2[i] = bq2[i];  Bqk2[256 + i] = bk2[i];
    }
  } else if (bid < 1028) {
    int idx = (bid - 1024) * 256 + t;
    if (idx < SEQ * 4) {
      int r = idx >> 2, w = idx & 3;
      unsigned long long bb = 0ull, oo = 0ull;
      for (int j = 0; j < 64; j++) {
        int c = w * 64 + j;
        if (c < SEQ) {
          oo |= (1ull << j);
          if (mask[r * SEQ + c] != 0) bb |= (1ull << j);
        }
      }
      bits[idx] = bb;
      ones[idx] = oo;
    }
  } else if (bid < 1092) {
    int b = bid - 1028, d = t;
    e[((size_t)b * SEQ + NPAT) * DMODEL + d] = f2b(cls[d] + pos[NPAT * DMODEL + d]);
  } else {
    const int ND = (MROWS * DMODEL) / 8;
    int i = (bid - 1092) * 256 + t;
    if (i < ND) {
      float4 a0 = ((const float4*)dec)[i * 2];
      float4 a1 = ((const float4*)dec)[i * 2 + 1];
      short8 o;
      o[0] = f2b(a0.x); o[1] = f2b(a0.y); o[2] = f2b(a0.z); o[3] = f2b(a0.w);
      o[4] = f2b(a1.x); o[5] = f2b(a1.y); o[6] = f2b(a1.z); o[7] = f2b(a1.w);
      ((short8*)dec_bf)[i] = o;
    }
  }
}

// ---------------------------------------------------------------------------
// Phase 1: conv (784) | qkv1 gemm (2364) | v2 gemm (788). A-major ordering.
// ---------------------------------------------------------------------------
__global__ __launch_bounds__(256) void phase1(
    const float* __restrict__ enc, const short* __restrict__ Wconv,
    const float* __restrict__ conv_b, const float* __restrict__ pos,
    short* __restrict__ e_bf,
    const short* __restrict__ dec_bf,
    const short* __restrict__ Wqkv1, const float* __restrict__ Bqkv1,
    short* __restrict__ qkv1,
    const short* __restrict__ Wv2, const float* __restrict__ bv2,
    short* __restrict__ v2)
{
  __shared__ char smem[32768];
  int bid = blockIdx.x;
  if (bid < 784) {
    conv64_body(smem, bid >> 2, bid & 3, enc, Wconv, conv_b, pos, e_bf);
  } else if (bid < 3148) {
    int idx = bid - 784;
    gemm64_body(smem, idx / 12, idx % 12, dec_bf, Wqkv1, Bqkv1, nullptr,
                nullptr, qkv1, 768, 256, 0);
  } else {
    int idx = bid - 3148;
    gemm64_body(smem, idx >> 2, idx & 3, dec_bf, Wv2, bv2, nullptr,
                nullptr, v2, 256, 256, 0);
  }
}

// ---------------------------------------------------------------------------
// Phase 2: attn1 (1024) | qk2 gemm (1576)
// ---------------------------------------------------------------------------
__global__ __launch_bounds__(256) void phase2(
    const short* __restrict__ qkv1, const unsigned long long* __restrict__ mones,
    short* __restrict__ o1,
    const short* __restrict__ e_bf, const short* __restrict__ Wqk2,
    const float* __restrict__ Bqk2, short* __restrict__ qk2)
{
  __shared__ char smem[37888];
  int bid = blockIdx.x;
  if (bid < 1024) {
    attn_body(smem, bid, qkv1, 768, qkv1 + 256, 768, qkv1 + 512, 768, mones, o1);
  } else {
    int idx = bid - 1024;
    gemm64_body(smem, idx >> 3, idx & 7, e_bf, Wqk2, Bqk2, nullptr,
                nullptr, qk2, 512, 256, 0);
  }
}

// ---------------------------------------------------------------------------
// Phase 3: attn2 (1024) | wo1+ln1 full-N gemm (197) -> x1b
// ---------------------------------------------------------------------------
__global__ __launch_bounds__(256) void phase3(
    const short* __restrict__ qk2, const short* __restrict__ v2,
    const unsigned long long* __restrict__ mbits, short* __restrict__ o2,
    const short* __restrict__ o1, const short* __restrict__ Wo1,
    const float* __restrict__ bo1, const short* __restrict__ dec_bf,
    const float* __restrict__ ln1_g, const float* __restrict__ ln1_b,
    short* __restrict__ x1b)
{
  __shared__ char smem[40960];
  int bid = blockIdx.x;
  if (bid < 1024) {
    attn_body(smem, bid, qk2, 512, qk2 + 256, 512, v2, 256, mbits, o2);
  } else {
    gemm_full_body(smem, bid - 1024, o1, Wo1, bo1, dec_bf, ln1_g, ln1_b,
                   x1b, nullptr, 256);
  }
}

// ---------------------------------------------------------------------------
// Standalone full-N GEMM+LN (wo2+ln2, ff2+ln3)
// ---------------------------------------------------------------------------
__global__ __launch_bounds__(256) void gemm_full_k(
    const short* __restrict__ A, const short* __restrict__ W,
    const float* __restrict__ bias, const short* __restrict__ resb,
    const float* __restrict__ g, const float* __restrict__ bln,
    short* __restrict__ outb, float* __restrict__ outfin, int K)
{
  __shared__ char smem[40960];
  gemm_full_body(smem, blockIdx.x, A, W, bias, resb, g, bln, outb, outfin, K);
}

// ---------------------------------------------------------------------------
// Standalone 64x64 GEMM, A-major 1-D grid (ff1)
// ---------------------------------------------------------------------------
__global__ __launch_bounds__(256) void gemm_k(
    const short* __restrict__ A, const short* __restrict__ W,
    const float* __restrict__ bias, const short* __restrict__ resb,
    float* __restrict__ outf, short* __restrict__ outb,
    int N, int K, int relu, int nby)
{
  __shared__ char smem[32768];
  gemm64_body(smem, blockIdx.x / nby, blockIdx.x % nby, A, W, bias, resb,
              outf, outb, N, K, relu);
}

// ---------------------------------------------------------------------------
extern "C" void kernel_launch(void* const* d_in, const int* in_sizes, int n_in,
                              void* d_out, int out_size, void* d_ws, size_t ws_size,
                              hipStream_t stream)
{
  const float* enc    = (const float*)d_in[0];
  const float* dec_in = (const float*)d_in[1];
  const int*   mask   = (const int*)  d_in[2];
  const float* conv_w = (const float*)d_in[3];
  const float* conv_b = (const float*)d_in[4];
  const float* cls    = (const float*)d_in[5];
  const float* pos    = (const float*)d_in[6];
  const float* ff_w1  = (const float*)d_in[7];
  const float* ff_b1  = (const float*)d_in[8];
  const float* ff_w2  = (const float*)d_in[9];
  const float* ff_b2  = (const float*)d_in[10];
  const float* ln1_g  = (const float*)d_in[11];
  const float* ln1_b  = (const float*)d_in[12];
  const float* ln2_g  = (const float*)d_in[13];
  const float* ln2_b  = (const float*)d_in[14];
  const float* ln3_g  = (const float*)d_in[15];
  const float* ln3_b  = (const float*)d_in[16];
  const float* a1_wq = (const float*)d_in[17]; const float* a1_bq = (const float*)d_in[18];
  const float* a1_wk = (const float*)d_in[19]; const float* a1_bk = (const float*)d_in[20];
  const float* a1_wv = (const float*)d_in[21]; const float* a1_bv = (const float*)d_in[22];
  const float* a1_wo = (const float*)d_in[23]; const float* a1_bo = (const float*)d_in[24];
  const float* a2_wq = (const float*)d_in[25]; const float* a2_bq = (const float*)d_in[26];
  const float* a2_wk = (const float*)d_in[27]; const float* a2_bk = (const float*)d_in[28];
  const float* a2_wv = (const float*)d_in[29]; const float* a2_bv = (const float*)d_in[30];
  const float* a2_wo = (const float*)d_in[31]; const float* a2_bo = (const float*)d_in[32];

  // ---- workspace layout ----
  char* wsB = (char*)d_ws;
  short* Wqkv1 = (short*)wsB;
  short* Wqk2  = Wqkv1 + 196608;
  short* Wv2   = Wqk2 + 131072;
  short* Wo1   = Wv2 + 65536;
  short* Wo2   = Wo1 + 65536;
  short* Wff1  = Wo2 + 65536;
  short* Wff2  = Wff1 + 262144;
  short* Wconv = Wff2 + 262144;
  float* Bqkv1 = (float*)(Wconv + 196608);
  float* Bqk2  = Bqkv1 + 768;
  unsigned long long* mbits = (unsigned long long*)(Bqk2 + 512);
  unsigned long long* mones = mbits + 788;

  const size_t MB = 1048576;
  short* dec_bf = (short*)(wsB + 3 * MB);
  short* e_bf   = (short*)(wsB + 10 * MB);
  short* qkv1   = (short*)(wsB + 17 * MB);
  short* o1     = (short*)(wsB + 37 * MB);
  short* qk2    = (short*)(wsB + 44 * MB);
  short* v2     = (short*)(wsB + 57 * MB);
  short* h_buf  = (short*)(wsB + 64 * MB);
  short* x1b    = (short*)(wsB + 97 * MB);
  short* x2b    = (short*)(wsB + 104 * MB);
  short* o2     = o1;

  dim3 blk(256);

  phase0<<<2668, blk, 0, stream>>>(
      a1_wq, a1_wk, a1_wv, a1_bq, a1_bk, a1_bv,
      a2_wq, a2_wk, a2_bq, a2_bk, a2_wv, a1_wo, a2_wo,
      ff_w1, ff_w2, conv_w,
      Wqkv1, Bqkv1, Wqk2, Bqk2, Wv2, Wo1, Wo2, Wff1, Wff2, Wconv,
      mask, mbits, mones, cls, pos, e_bf, dec_in, dec_bf);

  phase1<<<3936, blk, 0, stream>>>(
      enc, Wconv, conv_b, pos, e_bf,
      dec_bf, Wqkv1, Bqkv1, qkv1, Wv2, a2_bv, v2);

  phase2<<<2600, blk, 0, stream>>>(
      qkv1, mones, o1, e_bf, Wqk2, Bqk2, qk2);

  phase3<<<1221, blk, 0, stream>>>(
      qk2, v2, mbits, o2, o1, Wo1, a1_bo, dec_bf, ln1_g, ln1_b, x1b);

  gemm_full_k<<<197, blk, 0, stream>>>(
      o2, Wo2, a2_bo, x1b, ln2_g, ln2_b, x2b, nullptr, 256);

  gemm_k<<<3152, blk, 0, stream>>>(
      x2b, Wff1, ff_b1, nullptr, nullptr, h_buf, FFDIM, 256, 1, 16);

  gemm_full_k<<<197, blk, 0, stream>>>(
      h_buf, Wff2, ff_b2, x2b, ln3_g, ln3_b, nullptr, (float*)d_out, 1024);
}

// Round 8
// 326.803 us; speedup vs baseline: 1.0367x; 1.0367x over previous
//
#include <hip/hip_runtime.h>
#include <hip/hip_bf16.h>
#include <math.h>

#define DMODEL 256
#define NH 8
#define DKH 32
#define SEQ 197
#define BATCH 64
#define NPAT 196
#define FFDIM 1024
#define KCONV 768
#define EPSLN 1e-5f
#define MROWS (BATCH * SEQ)  // 12608 = 197*64
#define SP 224               // SEQ padded to 7 super-tiles of 32

typedef __attribute__((ext_vector_type(8))) short short8;
typedef __attribute__((ext_vector_type(4))) short short4v;
typedef __attribute__((ext_vector_type(4))) float floatx4;

__device__ inline short f2b(float f) {
  unsigned u = __float_as_uint(f);
  unsigned r = (u + 0x7FFFu + ((u >> 16) & 1u)) >> 16;
  return (short)r;
}
__device__ inline float b2f(short s) {
  return __uint_as_float(((unsigned)(unsigned short)s) << 16);
}

// async global->LDS 16B DMA (lds dest: wave-uniform base + lane*16)
typedef const __attribute__((address_space(1))) unsigned int gu32;
typedef __attribute__((address_space(3))) unsigned int lu32;
__device__ __forceinline__ void gl_lds16(const void* g, void* l) {
  __builtin_amdgcn_global_load_lds((gu32*)g, (lu32*)l, 16, 0, 0);
}

// ---------------------------------------------------------------------------
// Pipelined 64x64 bf16 MFMA GEMM body, BK=64, double-buffered LDS.
// ---------------------------------------------------------------------------
__device__ __forceinline__ void gemm64_body(
    char* smem, int bx, int by,
    const short* __restrict__ A, const short* __restrict__ W,
    const float* __restrict__ bias, const short* __restrict__ resb,
    float* __restrict__ outf, short* __restrict__ outb,
    int N, int K, int relu)
{
  short* Al = (short*)smem;            // 2 x 4096 shorts
  short* Bl = (short*)(smem + 16384);  // 2 x 4096 shorts
  const int t = threadIdx.x;
  const int wave = t >> 6, lane = t & 63;
  const int wm = (wave & 1) * 32, wn = (wave >> 1) * 32;
  const int ml = lane & 15, quad = lane >> 4;
  const int m7 = ml & 7;
  const int m0 = bx * 64, n0 = by * 64;

  const int rs = t >> 3;
  const int cs = (t & 7) ^ (rs & 7);
  const short* gA0 = A + (size_t)(m0 + rs) * K + cs * 8;
  const short* gA1 = A + (size_t)(m0 + rs + 32) * K + cs * 8;
  const short* gB0 = W + (size_t)(n0 + rs) * K + cs * 8;
  const short* gB1 = W + (size_t)(n0 + rs + 32) * K + cs * 8;

  int offA[2][2], offB[2][2];
#pragma unroll
  for (int kk = 0; kk < 2; kk++)
#pragma unroll
    for (int i = 0; i < 2; i++) {
      int ra = wm + i * 16 + ml;
      offA[kk][i] = ra * 64 + (((kk * 4 + quad) ^ m7) * 8);
      int rb = wn + i * 16 + ml;
      offB[kk][i] = rb * 64 + (((kk * 4 + quad) ^ m7) * 8);
    }

  floatx4 z = {0.f, 0.f, 0.f, 0.f};
  floatx4 acc[2][2] = {{z, z}, {z, z}};

  const int niter = K >> 6;
  gl_lds16(gA0, Al + t * 8);
  gl_lds16(gA1, Al + t * 8 + 2048);
  gl_lds16(gB0, Bl + t * 8);
  gl_lds16(gB1, Bl + t * 8 + 2048);
  for (int k = 0; k < niter; k++) {
    int cur = k & 1;
    if (k + 1 < niter) {
      int nb = (cur ^ 1) * 4096;
      int k0 = (k + 1) << 6;
      gl_lds16(gA0 + k0, Al + nb + t * 8);
      gl_lds16(gA1 + k0, Al + nb + t * 8 + 2048);
      gl_lds16(gB0 + k0, Bl + nb + t * 8);
      gl_lds16(gB1 + k0, Bl + nb + t * 8 + 2048);
      __builtin_amdgcn_s_waitcnt(0x0F74);  // vmcnt(4)
    } else {
      __builtin_amdgcn_s_waitcnt(0x0F70);  // vmcnt(0)
    }
    __asm__ volatile("s_barrier" ::: "memory");
    const short* Ac = Al + cur * 4096;
    const short* Bc = Bl + cur * 4096;
#pragma unroll
    for (int kk = 0; kk < 2; kk++) {
      short8 a0 = *(const short8*)&Ac[offA[kk][0]];
      short8 a1 = *(const short8*)&Ac[offA[kk][1]];
      short8 b0 = *(const short8*)&Bc[offB[kk][0]];
      short8 b1 = *(const short8*)&Bc[offB[kk][1]];
      acc[0][0] = __builtin_amdgcn_mfma_f32_16x16x32_bf16(a0, b0, acc[0][0], 0, 0, 0);
      acc[0][1] = __builtin_amdgcn_mfma_f32_16x16x32_bf16(a0, b1, acc[0][1], 0, 0, 0);
      acc[1][0] = __builtin_amdgcn_mfma_f32_16x16x32_bf16(a1, b0, acc[1][0], 0, 0, 0);
      acc[1][1] = __builtin_amdgcn_mfma_f32_16x16x32_bf16(a1, b1, acc[1][1], 0, 0, 0);
    }
    __asm__ volatile("s_barrier" ::: "memory");
  }
#pragma unroll
  for (int i = 0; i < 2; i++)
#pragma unroll
    for (int j = 0; j < 2; j++)
#pragma unroll
      for (int rr = 0; rr < 4; rr++) {
        int row = m0 + wm + i * 16 + quad * 4 + rr;
        int col = n0 + wn + j * 16 + ml;
        float v = acc[i][j][rr] + bias[col];
        if (resb) v += b2f(resb[(size_t)row * N + col]);
        if (relu) v = fmaxf(v, 0.f);
        if (outf) outf[(size_t)row * N + col] = v;
        if (outb) outb[(size_t)row * N + col] = f2b(v);
      }
}

// ---------------------------------------------------------------------------
// Full-N (256) GEMM + fused LayerNorm epilogue. Block = 64 rows x 256 cols,
// BK=32, double-buffered (40 KB LDS), vmcnt(5) prefetch + raw s_barrier.
// Swizzle (ml^(ml>>2))&3 gives uniform bank-group spread on b128 reads.
// ---------------------------------------------------------------------------
__device__ __forceinline__ void gemm_full_body(
    char* smem, int bx,
    const short* __restrict__ A, const short* __restrict__ W,
    const float* __restrict__ bias, const short* __restrict__ resb,
    const float* __restrict__ g, const float* __restrict__ bln,
    short* __restrict__ outb, float* __restrict__ outfin, int K)
{
  short* Al = (short*)smem;           // 2 x 2048 shorts (64x32)
  short* Bl = (short*)(smem + 8192);  // 2 x 8192 shorts (256x32)
  const int t = threadIdx.x;
  const int wave = t >> 6, lane = t & 63;
  const int ml = lane & 15, quad = lane >> 4;
  const int m0 = bx * 64;

  const int rs = t >> 2;                              // 0..63
  const int cs = (t & 3) ^ ((rs ^ (rs >> 2)) & 3);    // global chunk (swizzled)
  const short* gA = A + (size_t)(m0 + rs) * K + cs * 8;
  const short* gB[4];
#pragma unroll
  for (int j = 0; j < 4; j++)
    gB[j] = W + (size_t)(j * 64 + rs) * K + cs * 8;

  const int sm = (ml ^ (ml >> 2)) & 3;
  const int offA = (wave * 16 + ml) * 32 + ((quad ^ sm) * 8);
  const int offBb = ml * 32 + ((quad ^ sm) * 8);  // + jj*512

  floatx4 zv = {0.f, 0.f, 0.f, 0.f};
  floatx4 acc[16];
#pragma unroll
  for (int jj = 0; jj < 16; jj++) acc[jj] = zv;

  const int niter = K >> 5;
  gl_lds16(gA, Al + t * 8);
#pragma unroll
  for (int j = 0; j < 4; j++) gl_lds16(gB[j], Bl + j * 2048 + t * 8);
  for (int k = 0; k < niter; k++) {
    int cur = k & 1;
    if (k + 1 < niter) {
      int k0 = (k + 1) << 5;
      int nbA = (cur ^ 1) * 2048, nbB = (cur ^ 1) * 8192;
      gl_lds16(gA + k0, Al + nbA + t * 8);
#pragma unroll
      for (int j = 0; j < 4; j++) gl_lds16(gB[j] + k0, Bl + nbB + j * 2048 + t * 8);
      __builtin_amdgcn_s_waitcnt(0x0F75);  // vmcnt(5)
    } else {
      __builtin_amdgcn_s_waitcnt(0x0F70);  // vmcnt(0)
    }
    __asm__ volatile("s_barrier" ::: "memory");
    const short* Ac = Al + cur * 2048;
    const short* Bc = Bl + cur * 8192;
    short8 a = *(const short8*)&Ac[offA];
#pragma unroll
    for (int jj = 0; jj < 16; jj++) {
      short8 b = *(const short8*)&Bc[offBb + jj * 512];
      acc[jj] = __builtin_amdgcn_mfma_f32_16x16x32_bf16(a, b, acc[jj], 0, 0, 0);
    }
    __asm__ volatile("s_barrier" ::: "memory");
  }

  // ---- epilogue: bias + residual, then per-row LayerNorm ----
  const int rbase = m0 + wave * 16 + quad * 4;
  float bias_r[16], g_r[16], bl_r[16];
#pragma unroll
  for (int jj = 0; jj < 16; jj++) {
    int c = jj * 16 + ml;
    bias_r[jj] = bias[c];
    g_r[jj] = g[c];
    bl_r[jj] = bln[c];
  }
#pragma unroll
  for (int jj = 0; jj < 16; jj++)
#pragma unroll
    for (int rr = 0; rr < 4; rr++)
      acc[jj][rr] += bias_r[jj] + b2f(resb[(size_t)(rbase + rr) * DMODEL + jj * 16 + ml]);
#pragma unroll
  for (int rr = 0; rr < 4; rr++) {
    float s = 0.f;
#pragma unroll
    for (int jj = 0; jj < 16; jj++) s += acc[jj][rr];
    s += __shfl_xor(s, 1); s += __shfl_xor(s, 2);
    s += __shfl_xor(s, 4); s += __shfl_xor(s, 8);
    float mean = s * (1.0f / DMODEL);
    float vs = 0.f;
#pragma unroll
    for (int jj = 0; jj < 16; jj++) {
      float d = acc[jj][rr] - mean;
      vs += d * d;
    }
    vs += __shfl_xor(vs, 1); vs += __shfl_xor(vs, 2);
    vs += __shfl_xor(vs, 4); vs += __shfl_xor(vs, 8);
    float inv = rsqrtf(vs * (1.0f / DMODEL) + EPSLN);
    int row = rbase + rr;
#pragma unroll
    for (int jj = 0; jj < 16; jj++) {
      float o = (acc[jj][rr] - mean) * inv * g_r[jj] + bl_r[jj];
      int col = jj * 16 + ml;
      if (outb) outb[(size_t)row * DMODEL + col] = f2b(o);
      if (outfin) outfin[(size_t)row * DMODEL + col] = o;
    }
  }
}

// ---------------------------------------------------------------------------
// Patch-embed conv as 64x64 MFMA GEMM body, BK=64, im2col from fp32 img.
// ---------------------------------------------------------------------------
__device__ __forceinline__ void conv64_body(
    char* smem, int bx, int by,
    const float* __restrict__ img, const short* __restrict__ W,
    const float* __restrict__ cb, const float* __restrict__ pos,
    short* __restrict__ e)
{
  short* Al = (short*)smem;           // 4096 shorts
  short* Bl = (short*)(smem + 8192);  // 4096 shorts
  const int t = threadIdx.x;
  const int wave = t >> 6, lane = t & 63;
  const int wm = (wave & 1) * 32, wn = (wave >> 1) * 32;
  const int ml = lane & 15, quad = lane >> 4;
  const int m7 = ml & 7;
  const int m0 = bx * 64, n0 = by * 64;

  int rA = t >> 3, cg = t & 7;
  int pr_off = cg >> 1;
  int px_off = (cg & 1) * 8;
  int csw = cg ^ (rA & 7);
  const float* baseA[2];
  short* lA[2];
#pragma unroll
  for (int p = 0; p < 2; p++) {
    int m = m0 + rA + p * 32;
    int b = m / NPAT, pp = m - b * NPAT;
    int py = pp / 14, px = pp - py * 14;
    baseA[p] = img + (size_t)b * 3 * 50176 + (size_t)(py * 16) * 224 + px * 16 + px_off;
    lA[p] = &Al[(rA + p * 32) * 64 + csw * 8];
  }
  int rs = t >> 3;
  int cs = (t & 7) ^ (rs & 7);
  const short* gB0 = W + (size_t)(n0 + rs) * KCONV + cs * 8;
  const short* gB1 = W + (size_t)(n0 + rs + 32) * KCONV + cs * 8;

  int offA[2][2], offB[2][2];
#pragma unroll
  for (int kk = 0; kk < 2; kk++)
#pragma unroll
    for (int i = 0; i < 2; i++) {
      int ra = wm + i * 16 + ml;
      offA[kk][i] = ra * 64 + (((kk * 4 + quad) ^ m7) * 8);
      int rb = wn + i * 16 + ml;
      offB[kk][i] = rb * 64 + (((kk * 4 + quad) ^ m7) * 8);
    }

  floatx4 z = {0.f, 0.f, 0.f, 0.f};
  floatx4 acc[2][2] = {{z, z}, {z, z}};

  for (int k0 = 0; k0 < KCONV; k0 += 64) {
    int ch = k0 >> 8;
    int rr0 = (k0 & 255) >> 4;
    __syncthreads();
    gl_lds16(gB0 + k0, Bl + t * 8);
    gl_lds16(gB1 + k0, Bl + t * 8 + 2048);
#pragma unroll
    for (int p = 0; p < 2; p++) {
      const float* ap = baseA[p] + (size_t)ch * 50176 + (rr0 + pr_off) * 224;
      float4 a0 = *(const float4*)ap;
      float4 a1 = *(const float4*)(ap + 4);
      short8 av;
      av[0] = f2b(a0.x); av[1] = f2b(a0.y); av[2] = f2b(a0.z); av[3] = f2b(a0.w);
      av[4] = f2b(a1.x); av[5] = f2b(a1.y); av[6] = f2b(a1.z); av[7] = f2b(a1.w);
      *(short8*)lA[p] = av;
    }
    __builtin_amdgcn_s_waitcnt(0x0F70);
    __syncthreads();
#pragma unroll
    for (int kk = 0; kk < 2; kk++) {
      short8 a0 = *(const short8*)&Al[offA[kk][0]];
      short8 a1 = *(const short8*)&Al[offA[kk][1]];
      short8 b0 = *(const short8*)&Bl[offB[kk][0]];
      short8 b1 = *(const short8*)&Bl[offB[kk][1]];
      acc[0][0] = __builtin_amdgcn_mfma_f32_16x16x32_bf16(a0, b0, acc[0][0], 0, 0, 0);
      acc[0][1] = __builtin_amdgcn_mfma_f32_16x16x32_bf16(a0, b1, acc[0][1], 0, 0, 0);
      acc[1][0] = __builtin_amdgcn_mfma_f32_16x16x32_bf16(a1, b0, acc[1][0], 0, 0, 0);
      acc[1][1] = __builtin_amdgcn_mfma_f32_16x16x32_bf16(a1, b1, acc[1][1], 0, 0, 0);
    }
  }
#pragma unroll
  for (int i = 0; i < 2; i++)
#pragma unroll
    for (int j = 0; j < 2; j++)
#pragma unroll
      for (int rr = 0; rr < 4; rr++) {
        int mrow = m0 + wm + i * 16 + quad * 4 + rr;
        int b2 = mrow / NPAT, p2 = mrow - b2 * NPAT;
        int col = n0 + wn + j * 16 + ml;
        e[((size_t)b2 * SEQ + p2) * DMODEL + col] =
            f2b(acc[i][j][rr] + cb[col] + pos[p2 * DMODEL + col]);
      }
}

// ---------------------------------------------------------------------------
// MFMA flash attention body, S^T formulation. One block per (b,h);
// wave w handles query tiles w, w+4, w+8, w+12 (13 tiles total).
// V^T staging: each wave writes 64 consecutive columns of one row
// (stride-1 shorts -> 2 lanes/bank, conflict-free).
// ---------------------------------------------------------------------------
__device__ __forceinline__ void attn_body(
    char* smem, int bh,
    const short* __restrict__ qp, int qstr,
    const short* __restrict__ kp, int kstr,
    const short* __restrict__ vp, int vstr,
    const unsigned long long* __restrict__ mbits,
    short* __restrict__ op)
{
  short (*ks)[40] = (short(*)[40])smem;                     // SP*40 = 17920 B
  short (*vt)[SP + 8] = (short(*)[SP + 8])(smem + 17920);   // 32*232 = 14848 B
  short* psw = (short*)(smem + 32768);                      // 4*640 = 5120 B
  int b = bh >> 3, h = bh & 7;
  int t = threadIdx.x;
  int wave = t >> 6, lane = t & 63;
  int ml = lane & 15, quad = lane >> 4;
  short* ps = psw + wave * 640;

  const short* kb = kp + (size_t)b * SEQ * kstr + h * DKH;
  const short* vb = vp + (size_t)b * SEQ * vstr + h * DKH;
  for (int idx = t; idx < SEQ * 4; idx += 256) {
    int s = idx >> 2, c = (idx & 3) * 8;
    *(short8*)&ks[s][c] = *(const short8*)(kb + (size_t)s * kstr + c);
  }
  // V^T: wave-uniform row group c, lane-consecutive column s (conflict-free)
  for (int idx = t; idx < 1024; idx += 256) {
    int s = ((idx >> 8) << 6) + (idx & 63);
    int c = ((idx >> 6) & 3) * 8;
    if (s < SEQ) {
      short8 v8 = *(const short8*)(vb + (size_t)s * vstr + c);
#pragma unroll
      for (int j = 0; j < 8; j++) vt[c + j][s] = v8[j];
    }
  }
  for (int idx = t; idx < DKH * (SP - SEQ); idx += 256) {
    int d = idx / (SP - SEQ), j = SEQ + idx - d * (SP - SEQ);
    vt[d][j] = 0;
  }
  __syncthreads();

  const float scale = 0.17677669529663687f;
  floatx4 z = {0.f, 0.f, 0.f, 0.f};

  for (int ti = wave; ti < 13; ti += 4) {
    int q0 = ti * 16;
    int qrow = q0 + ml;
    int qc = qrow < SEQ ? qrow : SEQ - 1;
    short8 qf = *(const short8*)(qp + ((size_t)b * SEQ + qc) * qstr + h * DKH + quad * 8);
    const unsigned long long* mrow = mbits + (size_t)qc * 4;

    floatx4 accO0 = z, accO1 = z;
    float mrun = -1e30f, lrun = 0.f;

    for (int st = 0; st < 7; st++) {
      int j0 = st * 32;
      short8 k0 = *(const short8*)&ks[j0 + ml][quad * 8];
      short8 k1 = *(const short8*)&ks[j0 + 16 + ml][quad * 8];
      floatx4 s0 = __builtin_amdgcn_mfma_f32_16x16x32_bf16(k0, qf, z, 0, 0, 0);
      floatx4 s1 = __builtin_amdgcn_mfma_f32_16x16x32_bf16(k1, qf, z, 0, 0, 0);
      unsigned long long mb = mrow[j0 >> 6] >> (j0 & 63);
      float sv[8];
#pragma unroll
      for (int r = 0; r < 4; r++) {
        int jl = quad * 4 + r;
        sv[r]     = ((mb >> jl) & 1ull)        ? s0[r] * scale : -1e38f;
        sv[4 + r] = ((mb >> (16 + jl)) & 1ull) ? s1[r] * scale : -1e38f;
      }
      float tm = sv[0];
#pragma unroll
      for (int i = 1; i < 8; i++) tm = fmaxf(tm, sv[i]);
      tm = fmaxf(tm, __shfl_xor(tm, 16));
      tm = fmaxf(tm, __shfl_xor(tm, 32));
      float nm = fmaxf(mrun, tm);
      float alpha = __expf(mrun - nm);
      float pv[8];
      float psum = 0.f;
#pragma unroll
      for (int i = 0; i < 8; i++) { pv[i] = __expf(sv[i] - nm); psum += pv[i]; }
      psum += __shfl_xor(psum, 16);
      psum += __shfl_xor(psum, 32);
      lrun = lrun * alpha + psum;
      mrun = nm;
      accO0 = accO0 * alpha;
      accO1 = accO1 * alpha;
      short4v p0, p1;
#pragma unroll
      for (int r = 0; r < 4; r++) { p0[r] = f2b(pv[r]); p1[r] = f2b(pv[4 + r]); }
      *(short4v*)&ps[ml * 40 + quad * 4]      = p0;
      *(short4v*)&ps[ml * 40 + 16 + quad * 4] = p1;
      __asm__ volatile("s_waitcnt lgkmcnt(0)" ::: "memory");
      short8 pf = *(const short8*)&ps[ml * 40 + quad * 8];
      short8 vf0 = *(const short8*)&vt[ml][j0 + quad * 8];
      short8 vf1 = *(const short8*)&vt[16 + ml][j0 + quad * 8];
      accO0 = __builtin_amdgcn_mfma_f32_16x16x32_bf16(vf0, pf, accO0, 0, 0, 0);
      accO1 = __builtin_amdgcn_mfma_f32_16x16x32_bf16(vf1, pf, accO1, 0, 0, 0);
    }
    if (qrow < SEQ) {
      float inv = 1.f / lrun;
      short* ob = op + ((size_t)b * SEQ + qrow) * DMODEL + h * DKH;
      short4v o0, o1;
#pragma unroll
      for (int r = 0; r < 4; r++) {
        o0[r] = f2b(accO0[r] * inv);
        o1[r] = f2b(accO1[r] * inv);
      }
      *(short4v*)(ob + quad * 4)      = o0;
      *(short4v*)(ob + 16 + quad * 4) = o1;
    }
  }
}

// ---------------------------------------------------------------------------
// Phase 0: weight prep + mask pack + cls row + dec fp32->bf16
// ---------------------------------------------------------------------------
__global__ __launch_bounds__(256) void phase0(
    const float* wq1, const float* wk1, const float* wv1,
    const float* bq1, const float* bk1, const float* bv1,
    const float* wq2, const float* wk2, const float* bq2, const float* bk2,
    const float* wv2s, const float* wo1, const float* wo2,
    const float* ffw1, const float* ffw2, const float* convw,
    short* Wqkv1, float* Bqkv1, short* Wqk2, float* Bqk2,
    short* Wv2, short* Wo1, short* Wo2, short* Wff1, short* Wff2, short* Wconv,
    const int* mask, unsigned long long* bits, unsigned long long* ones,
    const float* cls, const float* pos, short* e,
    const float* dec, short* dec_bf)
{
  int bid = blockIdx.x;
  int t = threadIdx.x;
  if (bid < 1024) {
    int i = bid * 256 + t;
    if (i < 65536) {
      Wqkv1[i] = f2b(wq1[i]); Wqkv1[65536 + i] = f2b(wk1[i]); Wqkv1[131072 + i] = f2b(wv1[i]);
      Wqk2[i] = f2b(wq2[i]);  Wqk2[65536 + i] = f2b(wk2[i]);
      Wv2[i] = f2b(wv2s[i]);  Wo1[i] = f2b(wo1[i]);  Wo2[i] = f2b(wo2[i]);
    }
    Wff1[i] = f2b(ffw1[i]); Wff2[i] = f2b(ffw2[i]);
    if (i < 196608) Wconv[i] = f2b(convw[i]);
    if (i < 256) {
      Bqkv1[i] = bq1[i]; Bqkv1[256 + i] = bk1[i]; Bqkv1[512 + i] = bv1[i];
      Bqk2[i] = bq2[i];  Bqk2[256 + i] = bk2[i];
    }
  } else if (bid < 1028) {
    int idx = (bid - 1024) * 256 + t;
    if (idx < SEQ * 4) {
      int r = idx >> 2, w = idx & 3;
      unsigned long long bb = 0ull, oo = 0ull;
      for (int j = 0; j < 64; j++) {
        int c = w * 64 + j;
        if (c < SEQ) {
          oo |= (1ull << j);
          if (mask[r * SEQ + c] != 0) bb |= (1ull << j);
        }
      }
      bits[idx] = bb;
      ones[idx] = oo;
    }
  } else if (bid < 1092) {
    int b = bid - 1028, d = t;
    e[((size_t)b * SEQ + NPAT) * DMODEL + d] = f2b(cls[d] + pos[NPAT * DMODEL + d]);
  } else {
    const int ND = (MROWS * DMODEL) / 8;
    int i = (bid - 1092) * 256 + t;
    if (i < ND) {
      float4 a0 = ((const float4*)dec)[i * 2];
      float4 a1 = ((const float4*)dec)[i * 2 + 1];
      short8 o;
      o[0] = f2b(a0.x); o[1] = f2b(a0.y); o[2] = f2b(a0.z); o[3] = f2b(a0.w);
      o[4] = f2b(a1.x); o[5] = f2b(a1.y); o[6] = f2b(a1.z); o[7] = f2b(a1.w);
      ((short8*)dec_bf)[i] = o;
    }
  }
}

// ---------------------------------------------------------------------------
// Phase 1: conv (784) | qkv1 gemm (2364) | v2 gemm (788). A-major ordering.
// ---------------------------------------------------------------------------
__global__ __launch_bounds__(256) void phase1(
    const float* __restrict__ enc, const short* __restrict__ Wconv,
    const float* __restrict__ conv_b, const float* __restrict__ pos,
    short* __restrict__ e_bf,
    const short* __restrict__ dec_bf,
    const short* __restrict__ Wqkv1, const float* __restrict__ Bqkv1,
    short* __restrict__ qkv1,
    const short* __restrict__ Wv2, const float* __restrict__ bv2,
    short* __restrict__ v2)
{
  __shared__ char smem[32768];
  int bid = blockIdx.x;
  if (bid < 784) {
    conv64_body(smem, bid >> 2, bid & 3, enc, Wconv, conv_b, pos, e_bf);
  } else if (bid < 3148) {
    int idx = bid - 784;
    gemm64_body(smem, idx / 12, idx % 12, dec_bf, Wqkv1, Bqkv1, nullptr,
                nullptr, qkv1, 768, 256, 0);
  } else {
    int idx = bid - 3148;
    gemm64_body(smem, idx >> 2, idx & 3, dec_bf, Wv2, bv2, nullptr,
                nullptr, v2, 256, 256, 0);
  }
}

// ---------------------------------------------------------------------------
// Phase 2: attn1 (512) | qk2 gemm (1576)
// ---------------------------------------------------------------------------
__global__ __launch_bounds__(256) void phase2(
    const short* __restrict__ qkv1, const unsigned long long* __restrict__ mones,
    short* __restrict__ o1,
    const short* __restrict__ e_bf, const short* __restrict__ Wqk2,
    const float* __restrict__ Bqk2, short* __restrict__ qk2)
{
  __shared__ char smem[37888];
  int bid = blockIdx.x;
  if (bid < 512) {
    attn_body(smem, bid, qkv1, 768, qkv1 + 256, 768, qkv1 + 512, 768, mones, o1);
  } else {
    int idx = bid - 512;
    gemm64_body(smem, idx >> 3, idx & 7, e_bf, Wqk2, Bqk2, nullptr,
                nullptr, qk2, 512, 256, 0);
  }
}

// ---------------------------------------------------------------------------
// Standalone attention (attn2)
// ---------------------------------------------------------------------------
__global__ __launch_bounds__(256) void attn_k(
    const short* __restrict__ qp, int qstr,
    const short* __restrict__ kp, int kstr,
    const short* __restrict__ vp, int vstr,
    const unsigned long long* __restrict__ mbits,
    short* __restrict__ op)
{
  __shared__ char smem[37888];
  attn_body(smem, blockIdx.x, qp, qstr, kp, kstr, vp, vstr, mbits, op);
}

// ---------------------------------------------------------------------------
// Standalone full-N GEMM+LN (wo1+ln1, wo2+ln2, ff2+ln3)
// ---------------------------------------------------------------------------
__global__ __launch_bounds__(256) void gemm_full_k(
    const short* __restrict__ A, const short* __restrict__ W,
    const float* __restrict__ bias, const short* __restrict__ resb,
    const float* __restrict__ g, const float* __restrict__ bln,
    short* __restrict__ outb, float* __restrict__ outfin, int K)
{
  __shared__ char smem[40960];
  gemm_full_body(smem, blockIdx.x, A, W, bias, resb, g, bln, outb, outfin, K);
}

// ---------------------------------------------------------------------------
// Standalone 64x64 GEMM, A-major 1-D grid (ff1)
// ---------------------------------------------------------------------------
__global__ __launch_bounds__(256) void gemm_k(
    const short* __restrict__ A, const short* __restrict__ W,
    const float* __restrict__ bias, const short* __restrict__ resb,
    float* __restrict__ outf, short* __restrict__ outb,
    int N, int K, int relu, int nby)
{
  __shared__ char smem[32768];
  gemm64_body(smem, blockIdx.x / nby, blockIdx.x % nby, A, W, bias, resb,
              outf, outb, N, K, relu);
}

// ---------------------------------------------------------------------------
extern "C" void kernel_launch(void* const* d_in, const int* in_sizes, int n_in,
                              void* d_out, int out_size, void* d_ws, size_t ws_size,
                              hipStream_t stream)
{
  const float* enc    = (const float*)d_in[0];
  const float* dec_in = (const float*)d_in[1];
  const int*   mask   = (const int*)  d_in[2];
  const float* conv_w = (const float*)d_in[3];
  const float* conv_b = (const float*)d_in[4];
  const float* cls    = (const float*)d_in[5];
  const float* pos    = (const float*)d_in[6];
  const float* ff_w1  = (const float*)d_in[7];
  const float* ff_b1  = (const float*)d_in[8];
  const float* ff_w2  = (const float*)d_in[9];
  const float* ff_b2  = (const float*)d_in[10];
  const float* ln1_g  = (const float*)d_in[11];
  const float* ln1_b  = (const float*)d_in[12];
  const float* ln2_g  = (const float*)d_in[13];
  const float* ln2_b  = (const float*)d_in[14];
  const float* ln3_g  = (const float*)d_in[15];
  const float* ln3_b  = (const float*)d_in[16];
  const float* a1_wq = (const float*)d_in[17]; const float* a1_bq = (const float*)d_in[18];
  const float* a1_wk = (const float*)d_in[19]; const float* a1_bk = (const float*)d_in[20];
  const float* a1_wv = (const float*)d_in[21]; const float* a1_bv = (const float*)d_in[22];
  const float* a1_wo = (const float*)d_in[23]; const float* a1_bo = (const float*)d_in[24];
  const float* a2_wq = (const float*)d_in[25]; const float* a2_bq = (const float*)d_in[26];
  const float* a2_wk = (const float*)d_in[27]; const float* a2_bk = (const float*)d_in[28];
  const float* a2_wv = (const float*)d_in[29]; const float* a2_bv = (const float*)d_in[30];
  const float* a2_wo = (const float*)d_in[31]; const float* a2_bo = (const float*)d_in[32];

  // ---- workspace layout ----
  char* wsB = (char*)d_ws;
  short* Wqkv1 = (short*)wsB;
  short* Wqk2  = Wqkv1 + 196608;
  short* Wv2   = Wqk2 + 131072;
  short* Wo1   = Wv2 + 65536;
  short* Wo2   = Wo1 + 65536;
  short* Wff1  = Wo2 + 65536;
  short* Wff2  = Wff1 + 262144;
  short* Wconv = Wff2 + 262144;
  float* Bqkv1 = (float*)(Wconv + 196608);
  float* Bqk2  = Bqkv1 + 768;
  unsigned long long* mbits = (unsigned long long*)(Bqk2 + 512);
  unsigned long long* mones = mbits + 788;

  const size_t MB = 1048576;
  short* dec_bf = (short*)(wsB + 3 * MB);
  short* e_bf   = (short*)(wsB + 10 * MB);
  short* qkv1   = (short*)(wsB + 17 * MB);
  short* o1     = (short*)(wsB + 37 * MB);
  short* qk2    = (short*)(wsB + 44 * MB);
  short* v2     = (short*)(wsB + 57 * MB);
  short* h_buf  = (short*)(wsB + 64 * MB);
  short* x1b    = (short*)(wsB + 97 * MB);
  short* x2b    = (short*)(wsB + 104 * MB);
  short* o2     = o1;

  dim3 blk(256);

  phase0<<<2668, blk, 0, stream>>>(
      a1_wq, a1_wk, a1_wv, a1_bq, a1_bk, a1_bv,
      a2_wq, a2_wk, a2_bq, a2_bk, a2_wv, a1_wo, a2_wo,
      ff_w1, ff_w2, conv_w,
      Wqkv1, Bqkv1, Wqk2, Bqk2, Wv2, Wo1, Wo2, Wff1, Wff2, Wconv,
      mask, mbits, mones, cls, pos, e_bf, dec_in, dec_bf);

  phase1<<<3936, blk, 0, stream>>>(
      enc, Wconv, conv_b, pos, e_bf,
      dec_bf, Wqkv1, Bqkv1, qkv1, Wv2, a2_bv, v2);

  phase2<<<2088, blk, 0, stream>>>(
      qkv1, mones, o1, e_bf, Wqk2, Bqk2, qk2);

  // wo1+ln1 (197 blocks) then attn2 (512 blocks) — separate allocations
  gemm_full_k<<<197, blk, 0, stream>>>(
      o1, Wo1, a1_bo, dec_bf, ln1_g, ln1_b, x1b, nullptr, 256);

  attn_k<<<512, blk, 0, stream>>>(
      qk2, 512, qk2 + 256, 512, v2, 256, mbits, o2);

  gemm_full_k<<<197, blk, 0, stream>>>(
      o2, Wo2, a2_bo, x1b, ln2_g, ln2_b, x2b, nullptr, 256);

  gemm_k<<<3152, blk, 0, stream>>>(
      x2b, Wff1, ff_b1, nullptr, nullptr, h_buf, FFDIM, 256, 1, 16);

  gemm_full_k<<<197, blk, 0, stream>>>(
      h_buf, Wff2, ff_b2, x2b, ln3_g, ln3_b, nullptr, (float*)d_out, 1024);
}